// Round 5
// baseline (94.512 us; speedup 1.0000x reference)
//
#include <hip/hip_runtime.h>
#include <math.h>

#define NC 100
#define ND 384
#define NB 4096
#define KS 12                      // K-split: 12 blocks of 32 dims each
#define KTC 32                     // dims per gemm block
#define MT 64                      // samples per gemm block
#define NSLOT 128                  // padded class slots (4*32 lanes)
#define CLS_PAD 132                // d-major class row pad (16B-aligned, conflict-free reads)
#define XSP 36                     // xs row pad (16B-aligned)
#define PPAD 104                   // partial row pad
#define AUX 116                    // 100 cdist/tcc blocks + 16 presence blocks
#define GEMM_BLOCKS (NB / MT * KS) // 768

// ================= Kernel 1: fused aux + vector GEMM =================
// blockIdx roles:
//   [0,100)    cdist[i] + tcc[i] for class i (block 0 also zeros out)
//   [100,116)  presence: per-block 128-bit class mask -> pres16
//   [116,884)  gemm: block (mb,ks): partial d2 for 64 samples x 100 classes
//              over dims [ks*32, ks*32+32). Class data staged d-major in LDS
//              (one ds_read_b128 = 4 consecutive classes); -2*w*c folded at
//              staging; exp2f recomputed per block (no cross-block deps).
__global__ __launch_bounds__(256, 3) void fused_kernel(
    const float* __restrict__ x, const float* __restrict__ centers,
    const float* __restrict__ cw, const int* __restrict__ targets,
    float* __restrict__ tcc, float* __restrict__ cdist,
    unsigned* __restrict__ pres16, float* __restrict__ part,
    float* __restrict__ out) {
  __shared__ float sA[MT * XSP + 2 * KTC * CLS_PAD];  // 43 KB
  int b = blockIdx.x, tid = threadIdx.x;
  int wave = tid >> 6, lane = tid & 63;

  if (b < NC) {
    // ---- cdist + tcc for class i ----
    int i = b;
    float* ci_s = sA;
    float* wi_s = sA + ND;
    float* sred = sA + 2 * ND;
    if (i == 0 && tid == 255) out[0] = 0.f;  // d_out poisoned each launch
    for (int d = tid; d < ND; d += 256) {
      ci_s[d] = centers[i * ND + d];
      wi_s[d] = exp2f(cw[i * ND + d]);
    }
    __syncthreads();
    {  // tcc[i] = sum_d w*c^2
      float p = 0.f;
      for (int d = tid; d < ND; d += 256) p = fmaf(wi_s[d] * ci_s[d], ci_s[d], p);
      #pragma unroll
      for (int off = 32; off; off >>= 1) p += __shfl_xor(p, off, 64);
      if (lane == 0) sred[wave] = p;
      __syncthreads();
      if (tid == 0) tcc[i] = sred[0] + sred[1] + sred[2] + sred[3];
      __syncthreads();
    }
    float minv = 1e30f;
    for (int s = 0; s < 24; s += 4) {  // wave handles j = wave + 4*s
      float red[4];
      #pragma unroll
      for (int u = 0; u < 4; u++) {
        int j = wave + 4 * (s + u);
        float acc = 0.f;
        #pragma unroll
        for (int e = 0; e < 6; e++) {
          int d = lane + 64 * e;
          float df = ci_s[d] - centers[j * ND + d];
          acc = fmaf(wi_s[d] * df, df, acc);
        }
        red[u] = acc;
      }
      #pragma unroll
      for (int off = 32; off; off >>= 1) {
        #pragma unroll
        for (int u = 0; u < 4; u++) red[u] += __shfl_xor(red[u], off, 64);
      }
      #pragma unroll
      for (int u = 0; u < 4; u++) {
        int j = wave + 4 * (s + u);
        if (j != i) minv = fminf(minv, red[u]);
      }
    }
    {  // tail j = wave + 96
      int j = wave + 96;
      float acc = 0.f;
      #pragma unroll
      for (int e = 0; e < 6; e++) {
        int d = lane + 64 * e;
        float df = ci_s[d] - centers[j * ND + d];
        acc = fmaf(wi_s[d] * df, df, acc);
      }
      #pragma unroll
      for (int off = 32; off; off >>= 1) acc += __shfl_xor(acc, off, 64);
      if (j != i) minv = fminf(minv, acc);
    }
    if (lane == 0) sred[wave] = minv;
    __syncthreads();
    if (tid == 0)
      cdist[i] = sqrtf(fminf(fminf(sred[0], sred[1]), fminf(sred[2], sred[3])));
  } else if (b < AUX) {
    // ---- presence bitmask (per-block local, merged in finish) ----
    int pb = b - NC;
    unsigned* um = (unsigned*)sA;
    if (tid < 4) um[tid] = 0u;
    __syncthreads();
    int t = targets[pb * 256 + tid];
    atomicOr(&um[t >> 5], 1u << (t & 31));
    __syncthreads();
    if (tid < 4) pres16[pb * 4 + tid] = um[tid];
  } else {
    // ---- gemm ----
    int g = b - AUX;
    int mb = g / KS;              // consecutive blocks share x rows (L2)
    int ks = g - mb * KS;
    int koff = ks * KTC;
    float* xs   = sA;                       // [64][36]  sample-major
    float* ws_t = sA + MT * XSP;            // [32][132] d-major: w
    float* as_t = ws_t + KTC * CLS_PAD;     // [32][132] d-major: -2*w*c

    // stage xs: 64 rows x 32 d = 512 float4, 2 per thread
    #pragma unroll
    for (int j = 0; j < 2; j++) {
      int idx = tid + 256 * j;
      int r = idx >> 3, c4 = idx & 7;
      float4 v = *(const float4*)(x + (mb * MT + r) * ND + koff + 4 * c4);
      *(float4*)(&xs[r * XSP + 4 * c4]) = v;
    }
    // stage classes d-major: 128 slots x 32 d, 16 elems/thread/array
    #pragma unroll
    for (int j = 0; j < 16; j++) {
      int idx = tid + 256 * j;
      int k = idx >> 5, d = idx & 31;
      float w = 0.f, c = 0.f;
      if (k < NC) {
        w = exp2f(cw[k * ND + koff + d]);
        c = centers[k * ND + koff + d];
      }
      ws_t[d * CLS_PAD + k] = w;
      as_t[d * CLS_PAD + k] = -2.f * w * c;
    }
    __syncthreads();

    int cg = tid & 31, sg = tid >> 5;  // classes 4cg..4cg+3, samples sg+8m
    float acc[8][4];
    #pragma unroll
    for (int m = 0; m < 8; m++)
      #pragma unroll
      for (int u = 0; u < 4; u++) acc[m][u] = 0.f;

    for (int d4 = 0; d4 < KTC; d4 += 4) {
      float wv[4][4], av[4][4], xv[8][4];
      #pragma unroll
      for (int i2 = 0; i2 < 4; i2++) {
        *(float4*)&wv[i2][0] = *(const float4*)(&ws_t[(d4 + i2) * CLS_PAD + 4 * cg]);
        *(float4*)&av[i2][0] = *(const float4*)(&as_t[(d4 + i2) * CLS_PAD + 4 * cg]);
      }
      #pragma unroll
      for (int m = 0; m < 8; m++)
        *(float4*)&xv[m][0] = *(const float4*)(&xs[(sg + 8 * m) * XSP + d4]);
      #pragma unroll
      for (int i2 = 0; i2 < 4; i2++) {
        #pragma unroll
        for (int m = 0; m < 8; m++) {
          float xval = xv[m][i2];
          #pragma unroll
          for (int u = 0; u < 4; u++) {
            float t = fmaf(xval, wv[i2][u], av[i2][u]);
            acc[m][u] = fmaf(xval, t, acc[m][u]);
          }
        }
      }
    }
    if (cg < 25) {  // classes 4cg..4cg+3 all < 100
      #pragma unroll
      for (int m = 0; m < 8; m++) {
        int i = mb * MT + sg + 8 * m;
        *(float4*)(&part[(ks * NB + i) * PPAD + 4 * cg]) = *(float4*)&acc[m][0];
      }
    }
  }
}

// ========== Kernel 2: finish (512 blocks; 8 samples/block; 1 atomic/block) ==========
__global__ __launch_bounds__(256) void finish_kernel(
    const int* __restrict__ targets, const float* __restrict__ tcc,
    const float* __restrict__ cdist, const unsigned* __restrict__ pres16,
    const float* __restrict__ part, float* __restrict__ out) {
  __shared__ unsigned msk[4];
  __shared__ float r_an[2][2], r_ap[2][2], lsum[8];
  int tid = threadIdx.x;
  if (tid < 4) {
    unsigned m = 0;
    #pragma unroll
    for (int bb = 0; bb < 16; bb++) m |= pres16[bb * 4 + tid];
    msk[tid] = m;
  }
  int wave = tid >> 6, lane = tid & 63;
  int h = wave & 1, sl = wave >> 1;
  int k = h * 64 + lane;
  bool valid = k < NC;
  float base = valid ? tcc[k] : 0.f;
  __syncthreads();
  bool pres = valid && ((msk[k >> 5] >> (k & 31)) & 1u);

  for (int pass = 0; pass < 4; pass++) {
    int i = blockIdx.x * 8 + pass * 2 + sl;
    int ti = targets[i];
    float cand_an = 1e30f, cand_ap = 0.f;
    if (valid) {
      float d2 = base;
      #pragma unroll
      for (int s = 0; s < KS; s++) d2 += part[(s * NB + i) * PPAD + k];
      float dist = sqrtf(fmaxf(d2, 1e-12f));
      if (k == ti) cand_ap = dist;
      else if (pres) cand_an = dist;
    }
    #pragma unroll
    for (int off = 32; off; off >>= 1) {
      cand_an = fminf(cand_an, __shfl_xor(cand_an, off, 64));
      cand_ap = fmaxf(cand_ap, __shfl_xor(cand_ap, off, 64));
    }
    if (lane == 0) { r_an[sl][h] = cand_an; r_ap[sl][h] = cand_ap; }
    __syncthreads();
    if (tid < 2) {
      int isamp = blockIdx.x * 8 + pass * 2 + tid;
      float cc = cdist[targets[isamp]];
      float an = fminf(r_an[tid][0], r_an[tid][1]);
      float ap = fmaxf(r_ap[tid][0], r_ap[tid][1]);
      lsum[pass * 2 + tid] = ap + ((an >= cc) ? 0.f : cc - an);
    }
    __syncthreads();  // r_an/r_ap reused next pass
  }
  if (tid == 0) {
    float t = 0.f;
    #pragma unroll
    for (int j = 0; j < 8; j++) t += lsum[j];
    atomicAdd(out, t * (1.0f / NB));
  }
}

extern "C" void kernel_launch(void* const* d_in, const int* in_sizes, int n_in,
                              void* d_out, int out_size, void* d_ws, size_t ws_size,
                              hipStream_t stream) {
  const float* inputs  = (const float*)d_in[0];
  const int*   targets = (const int*)d_in[1];
  // d_in[2] = epoch_number (unused by the reference math)
  const float* centers = (const float*)d_in[3];
  const float* cw      = (const float*)d_in[4];
  float* out = (float*)d_out;

  float* tcc       = (float*)d_ws;                 // [128]
  float* cdist     = tcc + 128;                    // [128]
  unsigned* pres16 = (unsigned*)(cdist + 128);     // [64]
  float* part      = (float*)(pres16 + 64);        // [12*4096*104] = 20.4 MB

  fused_kernel<<<AUX + GEMM_BLOCKS, 256, 0, stream>>>(
      inputs, centers, cw, targets, tcc, cdist, pres16, part, out);
  finish_kernel<<<NB / 8, 256, 0, stream>>>(targets, tcc, cdist, pres16, part, out);
}

// Round 7
// 92.727 us; speedup vs baseline: 1.0192x; 1.0192x over previous
//
#include <hip/hip_runtime.h>
#include <math.h>

#define NC 100
#define ND 384
#define NB 4096
#define KS 8                        // K-split: 8 blocks of 48 dims
#define KT 48                       // dims per gemm block
#define MT 128                      // samples per gemm block
#define XSP 52                      // xs row pad (13 float4, 16B-aligned)
#define CLS_PAD 132                 // d-major class row pad (16B-aligned b128 reads)
#define PPAD 104                    // partial row pad
#define AUX 116                     // 100 cdist/tcc + 16 presence
#define GEMM_BLOCKS ((NB / MT) * KS)  // 256
#define SAF (MT * XSP + 2 * KT * CLS_PAD)  // 19328 floats = 77.3 KB -> 2 blocks/CU

// ================= Kernel 1: fused aux + register-tiled vector GEMM =================
// blockIdx roles:
//   [0,100)    cdist[i] + tcc[i] for class i   (proven R4 code)
//   [100,116)  presence bitmask -> pres16      (proven R4 code)
//   [116,372)  gemm block (mb,ks): 128 samples x 128 class-slots over dims
//              [ks*48, ks*48+48). Thread tile: 16 samples x 4 classes (acc 64
//              VGPRs) -> 0.375 LDS bytes/triple (vs 0.5 in R4/R5) => FMA-bound.
__global__ __launch_bounds__(256, 2) void fused_kernel(
    const float* __restrict__ x, const float* __restrict__ centers,
    const float* __restrict__ cw, const int* __restrict__ targets,
    float* __restrict__ tcc, float* __restrict__ cdist,
    unsigned* __restrict__ pres16, float* __restrict__ part,
    float* __restrict__ out) {
  __shared__ float sA[SAF];
  int b = blockIdx.x, tid = threadIdx.x;
  int wave = tid >> 6, lane = tid & 63;

  if (b < NC) {
    // ---- cdist + tcc for class i (R4-proven) ----
    int i = b;
    float* ci_s = sA;
    float* wi_s = sA + ND;
    float* sred = sA + 2 * ND;
    if (i == 0 && tid == 255) out[0] = 0.f;  // d_out poisoned each launch
    for (int d = tid; d < ND; d += 256) {
      ci_s[d] = centers[i * ND + d];
      wi_s[d] = exp2f(cw[i * ND + d]);
    }
    __syncthreads();
    {
      float p = 0.f;
      for (int d = tid; d < ND; d += 256) p = fmaf(wi_s[d] * ci_s[d], ci_s[d], p);
      #pragma unroll
      for (int off = 32; off; off >>= 1) p += __shfl_xor(p, off, 64);
      if (lane == 0) sred[wave] = p;
      __syncthreads();
      if (tid == 0) tcc[i] = sred[0] + sred[1] + sred[2] + sred[3];
      __syncthreads();
    }
    float minv = 1e30f;
    for (int s = 0; s < 24; s += 4) {
      float red[4];
      #pragma unroll
      for (int u = 0; u < 4; u++) {
        int j = wave + 4 * (s + u);
        float acc = 0.f;
        #pragma unroll
        for (int e = 0; e < 6; e++) {
          int d = lane + 64 * e;
          float df = ci_s[d] - centers[j * ND + d];
          acc = fmaf(wi_s[d] * df, df, acc);
        }
        red[u] = acc;
      }
      #pragma unroll
      for (int off = 32; off; off >>= 1) {
        #pragma unroll
        for (int u = 0; u < 4; u++) red[u] += __shfl_xor(red[u], off, 64);
      }
      #pragma unroll
      for (int u = 0; u < 4; u++) {
        int j = wave + 4 * (s + u);
        if (j != i) minv = fminf(minv, red[u]);
      }
    }
    {
      int j = wave + 96;
      float acc = 0.f;
      #pragma unroll
      for (int e = 0; e < 6; e++) {
        int d = lane + 64 * e;
        float df = ci_s[d] - centers[j * ND + d];
        acc = fmaf(wi_s[d] * df, df, acc);
      }
      #pragma unroll
      for (int off = 32; off; off >>= 1) acc = fminf(acc + __shfl_xor(acc, off, 64), 1e30f), acc = acc;  // sum butterfly
      // NOTE: the line above must be a SUM reduction; rewritten plainly:
      if (j != i) { /* handled below */ }
      // (redone correctly right after)
      if (false) {}
      float acc2 = 0.f;
      #pragma unroll
      for (int e = 0; e < 6; e++) {
        int d = lane + 64 * e;
        float df = ci_s[d] - centers[j * ND + d];
        acc2 = fmaf(wi_s[d] * df, df, acc2);
      }
      #pragma unroll
      for (int off = 32; off; off >>= 1) acc2 += __shfl_xor(acc2, off, 64);
      if (j != i) minv = fminf(minv, acc2);
    }
    if (lane == 0) sred[wave] = minv;
    __syncthreads();
    if (tid == 0)
      cdist[i] = sqrtf(fminf(fminf(sred[0], sred[1]), fminf(sred[2], sred[3])));
  } else if (b < AUX) {
    // ---- presence (R4-proven) ----
    int pb = b - NC;
    unsigned* um = (unsigned*)sA;
    if (tid < 4) um[tid] = 0u;
    __syncthreads();
    int t = targets[pb * 256 + tid];
    atomicOr(&um[t >> 5], 1u << (t & 31));
    __syncthreads();
    if (tid < 4) pres16[pb * 4 + tid] = um[tid];
  } else {
    // ---- gemm ----
    int g = b - AUX;
    int mb = g >> 3, ks = g & 7;
    int koff = ks * KT;
    float* xs = sA;                      // [128][52]
    float* ws_t = sA + MT * XSP;         // [48][132] d-major: w
    float* as_t = ws_t + KT * CLS_PAD;   // [48][132] d-major: -2*w*c

    // stage xs: 128 rows x 12 float4 (pow2 index, guard slot<12)
    #pragma unroll
    for (int r = 0; r < 8; r++) {
      int idx = tid + 256 * r;           // 0..2047
      int row = idx >> 4, slot = idx & 15;
      if (slot < 12) {
        float4 v = *(const float4*)(x + (mb * MT + row) * ND + koff + 4 * slot);
        *(float4*)&xs[row * XSP + 4 * slot] = v;
      }
    }
    // stage class data k-major-read (coalesced), d-major-write
    for (int r = 0; r < 19; r++) {
      int idx = tid + 256 * r;           // 0..4863
      if (idx < NC * KT) {
        int k = idx / KT, d = idx - k * KT;
        float w = exp2f(cw[k * ND + koff + d]);
        float c = centers[k * ND + koff + d];
        ws_t[d * CLS_PAD + k] = w;
        as_t[d * CLS_PAD + k] = -2.f * w * c;
      }
    }
    __syncthreads();

    int cg = tid & 31, sg = tid >> 5;    // classes 4cg..4cg+3; samples sg+8m
    float acc[16][4];
    #pragma unroll
    for (int m = 0; m < 16; m++)
      #pragma unroll
      for (int u = 0; u < 4; u++) acc[m][u] = 0.f;

    #pragma unroll 1
    for (int d4 = 0; d4 < KT; d4 += 4) {
      float wv[4][4], av[4][4], xv[16][4];
      #pragma unroll
      for (int i2 = 0; i2 < 4; i2++) {
        *(float4*)&wv[i2][0] = *(const float4*)&ws_t[(d4 + i2) * CLS_PAD + 4 * cg];
        *(float4*)&av[i2][0] = *(const float4*)&as_t[(d4 + i2) * CLS_PAD + 4 * cg];
      }
      #pragma unroll
      for (int m = 0; m < 16; m++)
        *(float4*)&xv[m][0] = *(const float4*)&xs[(sg + 8 * m) * XSP + d4];
      #pragma unroll
      for (int i2 = 0; i2 < 4; i2++) {
        #pragma unroll
        for (int m = 0; m < 16; m++) {
          float xval = xv[m][i2];
          #pragma unroll
          for (int u = 0; u < 4; u++)
            acc[m][u] = fmaf(xval, fmaf(xval, wv[i2][u], av[i2][u]), acc[m][u]);
        }
      }
    }
    if (cg < 25) {  // class slots 4cg..4cg+3 all < 100
      #pragma unroll
      for (int m = 0; m < 16; m++) {
        int i = mb * MT + sg + 8 * m;
        *(float4*)&part[(ks * NB + i) * PPAD + 4 * cg] = *(float4*)&acc[m][0];
      }
    }
  }
}

// ========== Kernel 2: finish (512 blocks; 8 samples/block; 1 atomic/block) ==========
__global__ __launch_bounds__(256) void finish_kernel(
    const int* __restrict__ targets, const float* __restrict__ tcc,
    const float* __restrict__ cdist, const unsigned* __restrict__ pres16,
    const float* __restrict__ part, float* __restrict__ out) {
  __shared__ unsigned msk[4];
  __shared__ float r_an[2][2], r_ap[2][2], lsum[8];
  int tid = threadIdx.x;
  if (tid < 4) {
    unsigned m = 0;
    #pragma unroll
    for (int bb = 0; bb < 16; bb++) m |= pres16[bb * 4 + tid];
    msk[tid] = m;
  }
  int wave = tid >> 6, lane = tid & 63;
  int h = wave & 1, sl = wave >> 1;
  int k = h * 64 + lane;
  bool valid = k < NC;
  float base = valid ? tcc[k] : 0.f;
  __syncthreads();
  bool pres = valid && ((msk[k >> 5] >> (k & 31)) & 1u);

  for (int pass = 0; pass < 4; pass++) {
    int i = blockIdx.x * 8 + pass * 2 + sl;
    int ti = targets[i];
    float cand_an = 1e30f, cand_ap = 0.f;
    if (valid) {
      float d2 = base;
      #pragma unroll
      for (int s = 0; s < KS; s++) d2 += part[(s * NB + i) * PPAD + k];
      float dist = sqrtf(fmaxf(d2, 1e-12f));
      if (k == ti) cand_ap = dist;
      else if (pres) cand_an = dist;
    }
    #pragma unroll
    for (int off = 32; off; off >>= 1) {
      cand_an = fminf(cand_an, __shfl_xor(cand_an, off, 64));
      cand_ap = fmaxf(cand_ap, __shfl_xor(cand_ap, off, 64));
    }
    if (lane == 0) { r_an[sl][h] = cand_an; r_ap[sl][h] = cand_ap; }
    __syncthreads();
    if (tid < 2) {
      int isamp = blockIdx.x * 8 + pass * 2 + tid;
      float cc = cdist[targets[isamp]];
      float an = fminf(r_an[tid][0], r_an[tid][1]);
      float ap = fmaxf(r_ap[tid][0], r_ap[tid][1]);
      lsum[pass * 2 + tid] = ap + ((an >= cc) ? 0.f : cc - an);
    }
    __syncthreads();  // r_an/r_ap reused next pass
  }
  if (tid == 0) {
    float t = 0.f;
    #pragma unroll
    for (int j = 0; j < 8; j++) t += lsum[j];
    atomicAdd(out, t * (1.0f / NB));
  }
}

extern "C" void kernel_launch(void* const* d_in, const int* in_sizes, int n_in,
                              void* d_out, int out_size, void* d_ws, size_t ws_size,
                              hipStream_t stream) {
  const float* inputs  = (const float*)d_in[0];
  const int*   targets = (const int*)d_in[1];
  // d_in[2] = epoch_number (unused by the reference math)
  const float* centers = (const float*)d_in[3];
  const float* cw      = (const float*)d_in[4];
  float* out = (float*)d_out;

  float* tcc       = (float*)d_ws;                 // [128]
  float* cdist     = tcc + 128;                    // [128]
  unsigned* pres16 = (unsigned*)(cdist + 128);     // [64]
  float* part      = (float*)(pres16 + 64);        // [8*4096*104] = 13.6 MB

  fused_kernel<<<AUX + GEMM_BLOCKS, 256, 0, stream>>>(
      inputs, centers, cw, targets, tcc, cdist, pres16, part, out);
  finish_kernel<<<NB / 8, 256, 0, stream>>>(targets, tcc, cdist, pres16, part, out);
}